// Round 11
// baseline (728.180 us; speedup 1.0000x reference)
//
#include <hip/hip_runtime.h>
#include <hip/hip_bf16.h>
#include <math.h>

#define LEAKY(x) ((x) >= 0.0f ? (x) : 0.2f * (x))
#define CHUNK 8192

typedef __attribute__((ext_vector_type(8))) short short8;
typedef __attribute__((ext_vector_type(4))) float f32x4;
typedef __attribute__((ext_vector_type(2))) int i32x2;

__device__ __forceinline__ float bf_lo(uint32_t u) { return __uint_as_float(u << 16); }
__device__ __forceinline__ float bf_hi(uint32_t u) { return __uint_as_float(u & 0xffff0000u); }
__device__ __forceinline__ uint32_t pack2(float a, float b) {
    __hip_bfloat162 h = __float22bfloat162_rn(make_float2(a, b));
    return *reinterpret_cast<uint32_t*>(&h);
}
__device__ __forceinline__ float pick4(const float4& v, int h)
{
    const float ab = (h & 1) ? v.y : v.x;
    const float cd = (h & 1) ? v.w : v.z;
    return (h & 2) ? cd : ab;
}

// ---------------------------------------------------------------------------
// w_prep: pack W (f32 [128 k][128 col]) into bf16 MFMA B-fragment order.
// ---------------------------------------------------------------------------
__global__ __launch_bounds__(256) void w_prep(
    const float* __restrict__ W, uint32_t* __restrict__ Wp)
{
    const int slot = blockIdx.x * 256 + threadIdx.x;
    if (slot >= 2048) return;
    const int kb = slot >> 9;
    const int cb = (slot >> 6) & 7;
    const int l  = slot & 63;
    const int k0 = kb * 32 + (l >> 4) * 8;
    const int col = cb * 16 + (l & 15);
    uint32_t u[4];
    #pragma unroll
    for (int p = 0; p < 4; ++p) {
        const float a = W[(size_t)(k0 + 2 * p) * 128 + col];
        const float b = W[(size_t)(k0 + 2 * p + 1) * 128 + col];
        u[p] = pack2(a, b);
    }
    *(uint4*)&Wp[(size_t)slot * 4] = make_uint4(u[0], u[1], u[2], u[3]);
}

// ---------------------------------------------------------------------------
// K1 (fused): blocks [0, nc): binA edge binning; blocks [nc, ...): MFMA GEMM.
// Independent work — binA overlaps the GEMM's memory streaming.
// ---------------------------------------------------------------------------
__global__ __launch_bounds__(256) void gemm_binA(
    const float* __restrict__ x, const uint32_t* __restrict__ Wp,
    const float* __restrict__ aks, const float* __restrict__ akn,
    uint32_t* __restrict__ xpb, float* __restrict__ attn_self,
    float* __restrict__ attn_nei, const int* __restrict__ ei,
    int2* __restrict__ stage, int* __restrict__ start_table,
    int* __restrict__ bucket_tot, int nc, int NB, int N, int E)
{
    __shared__ float xs[64][133];
    __shared__ int lh[512], lex[512], ss[256];
    const int t = threadIdx.x;

    if (blockIdx.x < nc) {                    // ---- binA part ----
        const int base = blockIdx.x * CHUNK;
        const int end  = min(E, base + CHUNK);

        for (int i = t; i < 512; i += 256) lh[i] = 0;
        __syncthreads();
        for (int i = base + t; i < end; i += 256)
            atomicAdd(&lh[((const int2*)ei)[i].y >> 8], 1);
        __syncthreads();

        const int v0 = lh[2 * t], v1 = lh[2 * t + 1];
        ss[t] = v0 + v1;
        __syncthreads();
        for (int d = 1; d < 256; d <<= 1) {
            const int add = (t >= d) ? ss[t - d] : 0;
            __syncthreads();
            ss[t] += add;
            __syncthreads();
        }
        const int ex = ss[t] - v0 - v1;
        lex[2 * t] = ex;
        lex[2 * t + 1] = ex + v0;
        __syncthreads();

        const size_t cbase = (size_t)blockIdx.x * (NB + 1);
        for (int b = t; b <= NB; b += 256) start_table[cbase + b] = base + lex[b];
        for (int b = t; b < NB; b += 256)
            if (lh[b]) atomicAdd(&bucket_tot[b], lh[b]);
        __syncthreads();

        for (int i = base + t; i < end; i += 256) {
            const int2 e2 = ((const int2*)ei)[i];
            const int slot = atomicAdd(&lex[e2.y >> 8], 1);
            stage[base + slot] = e2;
        }
        return;
    }

    // ---- GEMM part ----
    const int blk = blockIdx.x - nc;
    const int w  = t >> 6;
    const int l  = t & 63;
    const int nb = blk * 64;

    const int row  = nb + w * 16 + (l & 15);
    const int rowc = min(row, N - 1);
    const int kg   = (l >> 4) * 8;
    const float* xrow = x + (size_t)rowc * 128 + kg;

    f32x4 acc[8] = {};
    #pragma unroll
    for (int kb = 0; kb < 4; ++kb) {
        const float4 x0 = *(const float4*)(xrow + kb * 32);
        const float4 x1 = *(const float4*)(xrow + kb * 32 + 4);
        union { short8 s; uint32_t u[4]; } A;
        A.u[0] = pack2(x0.x, x0.y); A.u[1] = pack2(x0.z, x0.w);
        A.u[2] = pack2(x1.x, x1.y); A.u[3] = pack2(x1.z, x1.w);
        #pragma unroll
        for (int cb = 0; cb < 8; ++cb) {
            union { short8 s; uint4 u; } B;
            B.u = *(const uint4*)&Wp[(((size_t)(kb * 8 + cb)) * 64 + l) * 4];
            acc[cb] = __builtin_amdgcn_mfma_f32_16x16x32_bf16(A.s, B.s, acc[cb], 0, 0, 0);
        }
    }

    const int r0 = (l >> 4) * 4;
    const int cl = l & 15;
    #pragma unroll
    for (int cb = 0; cb < 8; ++cb)
        #pragma unroll
        for (int r = 0; r < 4; ++r)
            xs[w * 16 + r0 + r][cb * 16 + cl] = acc[cb][r];
    __syncthreads();

    #pragma unroll
    for (int i = 0; i < 16; ++i) {
        const int idx = t + i * 256;           // 0..4095
        const int n = idx >> 6, q = idx & 63;
        const int gn = nb + n;
        if (gn < N)
            xpb[(size_t)gn * 64 + q] = pack2(xs[n][2 * q], xs[n][2 * q + 1]);
    }

    {
        const int n = t & 63, h = t >> 6;
        const int gn = nb + n;
        if (gn < N) {
            float sv = 0.0f, sn = 0.0f;
            #pragma unroll
            for (int c = 0; c < 32; ++c) {
                const float v = xs[n][h * 32 + c];
                sv = fmaf(v, aks[c * 4 + h], sv);
                sn = fmaf(v, akn[c * 4 + h], sn);
            }
            attn_self[(size_t)gn * 4 + h] = sv;
            attn_nei [(size_t)gn * 4 + h] = sn;
        }
    }
}

// ---------------------------------------------------------------------------
// binB: one block per bucket; inline bucket-offset reduce (replaces the
// serializing bucket_scan launch); per-node counts/scan/scatter in LDS.
// ---------------------------------------------------------------------------
__global__ __launch_bounds__(256) void binB(
    const int2* __restrict__ stage, const int* __restrict__ start_table,
    const int* __restrict__ bucket_tot, int* __restrict__ offsets,
    int* __restrict__ csr_src, int nc, int NB, int N, int E)
{
    __shared__ int s0[256], cum[257], ss[256], lcnt[256], lcur[256], red[256];
    const int t  = threadIdx.x;
    const int b  = blockIdx.x;
    const int lo = b << 8;
    const int nn = min(N, lo + 256) - lo;

    // bucket_off[b] = sum_{i<b} bucket_tot[i]  (tiny L2-hot reduce)
    int part = 0;
    for (int i = t; i < b; i += 256) part += bucket_tot[i];
    red[t] = part;
    if (t == 0 && b == 0) offsets[N] = E;

    int len = 0;
    if (t < nc) {
        const size_t cb = (size_t)t * (NB + 1);
        const int a0 = start_table[cb + b];
        s0[t] = a0;
        len   = start_table[cb + b + 1] - a0;
    }
    ss[t] = len;
    lcnt[t] = 0;
    __syncthreads();
    for (int d = 128; d > 0; d >>= 1) {
        if (t < d) red[t] += red[t + d];
        __syncthreads();
    }
    const int boff = red[0];
    for (int d = 1; d < 256; d <<= 1) {
        const int add = (t >= d) ? ss[t - d] : 0;
        __syncthreads();
        ss[t] += add;
        __syncthreads();
    }
    if (t == 0) cum[0] = 0;
    cum[t + 1] = ss[t];
    __syncthreads();
    const int T = cum[nc];

    for (int g = t; g < T; g += 256) {
        int loc = 0, hic = nc - 1;
        while (loc < hic) {
            const int mid = (loc + hic + 1) >> 1;
            if (cum[mid] <= g) loc = mid; else hic = mid - 1;
        }
        const i32x2 e = __builtin_nontemporal_load(
            (const i32x2*)stage + (s0[loc] + (g - cum[loc])));
        atomicAdd(&lcnt[e.y - lo], 1);
    }
    __syncthreads();

    const int v = lcnt[t];
    ss[t] = v;
    __syncthreads();
    for (int d = 1; d < 256; d <<= 1) {
        const int add = (t >= d) ? ss[t - d] : 0;
        __syncthreads();
        ss[t] += add;
        __syncthreads();
    }
    const int nodeoff = boff + ss[t] - v;
    lcur[t] = nodeoff;
    if (t < nn) offsets[lo + t] = nodeoff;
    __syncthreads();

    for (int g = t; g < T; g += 256) {
        int loc = 0, hic = nc - 1;
        while (loc < hic) {
            const int mid = (loc + hic + 1) >> 1;
            if (cum[mid] <= g) loc = mid; else hic = mid - 1;
        }
        const i32x2 e = __builtin_nontemporal_load(
            (const i32x2*)stage + (s0[loc] + (g - cum[loc])));
        const int slot = atomicAdd(&lcur[e.y - lo], 1);
        csr_src[slot] = e.x;
    }
}

// ---------------------------------------------------------------------------
// aggregate v5: round-8/10 memory pattern (one wave/node, 4 B/lane xpb
// gathers, unroll 8) but wave-uniform edge metadata moved to the SCALAR
// pipe: srcp/attn row via readfirstlane -> s_load; 32-bit voffsets.
// ---------------------------------------------------------------------------
__global__ __launch_bounds__(256) void aggregate(
    const int* __restrict__ csr_src, const int* __restrict__ offsets,
    const uint32_t* __restrict__ xpb, const float* __restrict__ attn_self,
    const float* __restrict__ attn_nei, const float* __restrict__ bias,
    float* __restrict__ out, float* __restrict__ alpha_out,
    float* __restrict__ inv_arr, int N, int E)
{
    const int lane = threadIdx.x & 63;
    int node = blockIdx.x * 4 + (threadIdx.x >> 6);
    if (node >= N) return;
    node = __builtin_amdgcn_readfirstlane(node);

    const int hL = lane >> 4;        // head of this lane's 2 channels
    const int c0 = 2 * lane;

    const float asH = attn_self[(size_t)node * 4 + hL];
    const float anH = attn_nei [(size_t)node * 4 + hL];
    const float eS  = __expf(LEAKY(asH + anH));
    float sumE = eS;
    const uint32_t* xpl = xpb + lane;            // per-lane column base
    const uint32_t uS = xpl[(uint32_t)node << 6];
    float acc0 = eS * bf_lo(uS), acc1 = eS * bf_hi(uS);

    const int off0 = __builtin_amdgcn_readfirstlane(offsets[node]);
    const int deg  = __builtin_amdgcn_readfirstlane(offsets[node + 1]) - off0;
    const int* srcp = csr_src + off0;

    for (int j = 0; j < deg; j += 8) {
        int s[8];
        #pragma unroll
        for (int k = 0; k < 8; ++k)
            s[k] = __builtin_amdgcn_readfirstlane(srcp[min(j + k, deg - 1)]);
        float4 an4[8];
        #pragma unroll
        for (int k = 0; k < 8; ++k)
            an4[k] = *(const float4*)&attn_nei[(uint32_t)s[k] * 4u];   // s_load
        uint32_t u[8];
        #pragma unroll
        for (int k = 0; k < 8; ++k) u[k] = xpl[(uint32_t)s[k] << 6];
        #pragma unroll
        for (int k = 0; k < 8; ++k) {
            const float v = (j + k < deg)
                ? __expf(LEAKY(asH + pick4(an4[k], hL))) : 0.0f;
            sumE += v;
            acc0 = fmaf(v, bf_lo(u[k]), acc0);
            acc1 = fmaf(v, bf_hi(u[k]), acc1);
        }
    }

    const float inv = 1.0f / sumE;
    union { float2 f; unsigned long long u; } o;
    o.f = make_float2(fmaf(acc0, inv, bias[c0]), fmaf(acc1, inv, bias[c0 + 1]));
    __builtin_nontemporal_store(o.u,
        (unsigned long long*)&out[(size_t)node * 128 + c0]);
    if ((lane & 15) == 0) {
        inv_arr[(size_t)node * 4 + hL] = inv;
        __builtin_nontemporal_store(eS * inv,
            &alpha_out[(size_t)(E + node) * 4 + hL]);
    }
}

// ---------------------------------------------------------------------------
// alpha for the E real edges: nt ei loads + nt alpha stores.
// ---------------------------------------------------------------------------
__global__ __launch_bounds__(256) void alpha_kernel(
    const int* __restrict__ ei, const float* __restrict__ attn_self,
    const float* __restrict__ attn_nei, const float* __restrict__ inv_arr,
    float* __restrict__ alpha_out, int E)
{
    const int i = blockIdx.x * 256 + threadIdx.x;
    if (i >= E) return;
    const i32x2 e2 = __builtin_nontemporal_load((const i32x2*)ei + i);
    const int src = e2.x, tgt = e2.y;
    const float4 as4 = *(const float4*)&attn_self[(size_t)tgt * 4];
    const float4 an4 = *(const float4*)&attn_nei[(size_t)src * 4];
    const float4 iv4 = *(const float4*)&inv_arr[(size_t)tgt * 4];
    f32x4 a;
    a.x = __expf(LEAKY(as4.x + an4.x)) * iv4.x;
    a.y = __expf(LEAKY(as4.y + an4.y)) * iv4.y;
    a.z = __expf(LEAKY(as4.z + an4.z)) * iv4.z;
    a.w = __expf(LEAKY(as4.w + an4.w)) * iv4.w;
    __builtin_nontemporal_store(a, (f32x4*)&alpha_out[(size_t)i * 4]);
}

// ---------------------------------------------------------------------------
extern "C" void kernel_launch(void* const* d_in, const int* in_sizes, int n_in,
                              void* d_out, int out_size, void* d_ws, size_t ws_size,
                              hipStream_t stream)
{
    const float* x    = (const float*)d_in[0];
    const int*   ei   = (const int*)d_in[1];
    const float* W    = (const float*)d_in[2];
    const float* aks  = (const float*)d_in[3];
    const float* akn  = (const float*)d_in[4];
    const float* bias = (const float*)d_in[5];

    const int N  = in_sizes[0] / 128;
    const int E  = in_sizes[1] / 2;
    const int NB = (N + 255) >> 8;
    const int nc = (E + CHUNK - 1) / CHUNK;

    float* out       = (float*)d_out;
    float* alpha_out = out + (size_t)N * 128;
    int2* stage      = (int2*)alpha_out;   // overlays alpha region (see r7 note)

    char* p = (char*)d_ws;
    auto alloc = [&](size_t bytes) {
        char* r = p;
        p += (bytes + 255) & ~(size_t)255;
        return r;
    };
    uint32_t* xpb       = (uint32_t*)alloc((size_t)N * 64 * 4);
    uint32_t* Wp        = (uint32_t*)alloc((size_t)2048 * 16);
    float* attn_self    = (float*)alloc((size_t)N * 4 * 4);
    float* attn_nei     = (float*)alloc((size_t)N * 4 * 4);
    float* inv_arr      = (float*)alloc((size_t)N * 4 * 4);
    int*   offsets      = (int*)alloc((size_t)(N + 1) * 4);
    int*   csr_src      = (int*)alloc((size_t)E * 4);
    int*   bucket_tot   = (int*)alloc((size_t)NB * 4);
    int*   start_table  = (int*)alloc((size_t)nc * (NB + 1) * 4);

    hipMemsetAsync(bucket_tot, 0, (size_t)NB * 4, stream);

    w_prep<<<8, 256, 0, stream>>>(W, Wp);
    gemm_binA<<<nc + (N + 63) / 64, 256, 0, stream>>>(
        x, Wp, aks, akn, xpb, attn_self, attn_nei,
        ei, stage, start_table, bucket_tot, nc, NB, N, E);
    binB<<<NB, 256, 0, stream>>>(stage, start_table, bucket_tot, offsets,
                                 csr_src, nc, NB, N, E);
    aggregate<<<(N + 3) / 4, 256, 0, stream>>>(csr_src, offsets, xpb,
                                               attn_self, attn_nei, bias, out,
                                               alpha_out, inv_arr, N, E);
    alpha_kernel<<<(E + 255) / 256, 256, 0, stream>>>(ei, attn_self, attn_nei,
                                                      inv_arr, alpha_out, E);
}

// Round 12
// 192.656 us; speedup vs baseline: 3.7797x; 3.7797x over previous
//
#include <hip/hip_runtime.h>
#include <hip/hip_bf16.h>
#include <math.h>

#define LEAKY(x) ((x) >= 0.0f ? (x) : 0.2f * (x))
#define CHUNK 8192

typedef __attribute__((ext_vector_type(8))) short short8;
typedef __attribute__((ext_vector_type(4))) float f32x4;
typedef __attribute__((ext_vector_type(2))) int i32x2;

__device__ __forceinline__ float bf_lo(uint32_t u) { return __uint_as_float(u << 16); }
__device__ __forceinline__ float bf_hi(uint32_t u) { return __uint_as_float(u & 0xffff0000u); }
__device__ __forceinline__ uint32_t pack2(float a, float b) {
    __hip_bfloat162 h = __float22bfloat162_rn(make_float2(a, b));
    return *reinterpret_cast<uint32_t*>(&h);
}

// ---------------------------------------------------------------------------
// w_prep: pack W (f32 [128 k][128 col]) into bf16 MFMA B-fragment order.
// ---------------------------------------------------------------------------
__global__ __launch_bounds__(256) void w_prep(
    const float* __restrict__ W, uint32_t* __restrict__ Wp)
{
    const int slot = blockIdx.x * 256 + threadIdx.x;
    if (slot >= 2048) return;
    const int kb = slot >> 9;
    const int cb = (slot >> 6) & 7;
    const int l  = slot & 63;
    const int k0 = kb * 32 + (l >> 4) * 8;
    const int col = cb * 16 + (l & 15);
    uint32_t u[4];
    #pragma unroll
    for (int p = 0; p < 4; ++p) {
        const float a = W[(size_t)(k0 + 2 * p) * 128 + col];
        const float b = W[(size_t)(k0 + 2 * p + 1) * 128 + col];
        u[p] = pack2(a, b);
    }
    *(uint4*)&Wp[(size_t)slot * 4] = make_uint4(u[0], u[1], u[2], u[3]);
}

// ---------------------------------------------------------------------------
// K1 (fused): blocks [0, nc): binA edge binning; blocks [nc, ...): MFMA GEMM.
// ---------------------------------------------------------------------------
__global__ __launch_bounds__(256) void gemm_binA(
    const float* __restrict__ x, const uint32_t* __restrict__ Wp,
    const float* __restrict__ aks, const float* __restrict__ akn,
    uint32_t* __restrict__ xpb, float* __restrict__ attn_self,
    float* __restrict__ attn_nei, const int* __restrict__ ei,
    int2* __restrict__ stage, int* __restrict__ start_table,
    int* __restrict__ bucket_tot, int nc, int NB, int N, int E)
{
    __shared__ float xs[64][133];
    __shared__ int lh[512], lex[512], ss[256];
    const int t = threadIdx.x;

    if (blockIdx.x < nc) {                    // ---- binA part ----
        const int base = blockIdx.x * CHUNK;
        const int end  = min(E, base + CHUNK);

        for (int i = t; i < 512; i += 256) lh[i] = 0;
        __syncthreads();
        for (int i = base + t; i < end; i += 256)
            atomicAdd(&lh[((const int2*)ei)[i].y >> 8], 1);
        __syncthreads();

        const int v0 = lh[2 * t], v1 = lh[2 * t + 1];
        ss[t] = v0 + v1;
        __syncthreads();
        for (int d = 1; d < 256; d <<= 1) {
            const int add = (t >= d) ? ss[t - d] : 0;
            __syncthreads();
            ss[t] += add;
            __syncthreads();
        }
        const int ex = ss[t] - v0 - v1;
        lex[2 * t] = ex;
        lex[2 * t + 1] = ex + v0;
        __syncthreads();

        const size_t cbase = (size_t)blockIdx.x * (NB + 1);
        for (int b = t; b <= NB; b += 256) start_table[cbase + b] = base + lex[b];
        for (int b = t; b < NB; b += 256)
            if (lh[b]) atomicAdd(&bucket_tot[b], lh[b]);
        __syncthreads();

        for (int i = base + t; i < end; i += 256) {
            const int2 e2 = ((const int2*)ei)[i];
            const int slot = atomicAdd(&lex[e2.y >> 8], 1);
            stage[base + slot] = e2;
        }
        return;
    }

    // ---- GEMM part ----
    const int blk = blockIdx.x - nc;
    const int w  = t >> 6;
    const int l  = t & 63;
    const int nb = blk * 64;

    const int row  = nb + w * 16 + (l & 15);
    const int rowc = min(row, N - 1);
    const int kg   = (l >> 4) * 8;
    const float* xrow = x + (size_t)rowc * 128 + kg;

    f32x4 acc[8] = {};
    #pragma unroll
    for (int kb = 0; kb < 4; ++kb) {
        const float4 x0 = *(const float4*)(xrow + kb * 32);
        const float4 x1 = *(const float4*)(xrow + kb * 32 + 4);
        union { short8 s; uint32_t u[4]; } A;
        A.u[0] = pack2(x0.x, x0.y); A.u[1] = pack2(x0.z, x0.w);
        A.u[2] = pack2(x1.x, x1.y); A.u[3] = pack2(x1.z, x1.w);
        #pragma unroll
        for (int cb = 0; cb < 8; ++cb) {
            union { short8 s; uint4 u; } B;
            B.u = *(const uint4*)&Wp[(((size_t)(kb * 8 + cb)) * 64 + l) * 4];
            acc[cb] = __builtin_amdgcn_mfma_f32_16x16x32_bf16(A.s, B.s, acc[cb], 0, 0, 0);
        }
    }

    const int r0 = (l >> 4) * 4;
    const int cl = l & 15;
    #pragma unroll
    for (int cb = 0; cb < 8; ++cb)
        #pragma unroll
        for (int r = 0; r < 4; ++r)
            xs[w * 16 + r0 + r][cb * 16 + cl] = acc[cb][r];
    __syncthreads();

    #pragma unroll
    for (int i = 0; i < 16; ++i) {
        const int idx = t + i * 256;           // 0..4095
        const int n = idx >> 6, q = idx & 63;
        const int gn = nb + n;
        if (gn < N)
            xpb[(size_t)gn * 64 + q] = pack2(xs[n][2 * q], xs[n][2 * q + 1]);
    }

    {
        const int n = t & 63, h = t >> 6;
        const int gn = nb + n;
        if (gn < N) {
            float sv = 0.0f, sn = 0.0f;
            #pragma unroll
            for (int c = 0; c < 32; ++c) {
                const float v = xs[n][h * 32 + c];
                sv = fmaf(v, aks[c * 4 + h], sv);
                sn = fmaf(v, akn[c * 4 + h], sn);
            }
            attn_self[(size_t)gn * 4 + h] = sv;
            attn_nei [(size_t)gn * 4 + h] = sn;
        }
    }
}

// ---------------------------------------------------------------------------
// binB: one block per bucket; inline bucket-offset reduce; per-node
// counts/scan/scatter in LDS; writes offsets[lo..hi) and csr_src.
// ---------------------------------------------------------------------------
__global__ __launch_bounds__(256) void binB(
    const int2* __restrict__ stage, const int* __restrict__ start_table,
    const int* __restrict__ bucket_tot, int* __restrict__ offsets,
    int* __restrict__ csr_src, int nc, int NB, int N, int E)
{
    __shared__ int s0[256], cum[257], ss[256], lcnt[256], lcur[256], red[256];
    const int t  = threadIdx.x;
    const int b  = blockIdx.x;
    const int lo = b << 8;
    const int nn = min(N, lo + 256) - lo;

    int part = 0;
    for (int i = t; i < b; i += 256) part += bucket_tot[i];
    red[t] = part;
    if (t == 0 && b == 0) offsets[N] = E;

    int len = 0;
    if (t < nc) {
        const size_t cb = (size_t)t * (NB + 1);
        const int a0 = start_table[cb + b];
        s0[t] = a0;
        len   = start_table[cb + b + 1] - a0;
    }
    ss[t] = len;
    lcnt[t] = 0;
    __syncthreads();
    for (int d = 128; d > 0; d >>= 1) {
        if (t < d) red[t] += red[t + d];
        __syncthreads();
    }
    const int boff = red[0];
    for (int d = 1; d < 256; d <<= 1) {
        const int add = (t >= d) ? ss[t - d] : 0;
        __syncthreads();
        ss[t] += add;
        __syncthreads();
    }
    if (t == 0) cum[0] = 0;
    cum[t + 1] = ss[t];
    __syncthreads();
    const int T = cum[nc];

    for (int g = t; g < T; g += 256) {
        int loc = 0, hic = nc - 1;
        while (loc < hic) {
            const int mid = (loc + hic + 1) >> 1;
            if (cum[mid] <= g) loc = mid; else hic = mid - 1;
        }
        const int2 e = stage[s0[loc] + (g - cum[loc])];
        atomicAdd(&lcnt[e.y - lo], 1);
    }
    __syncthreads();

    const int v = lcnt[t];
    ss[t] = v;
    __syncthreads();
    for (int d = 1; d < 256; d <<= 1) {
        const int add = (t >= d) ? ss[t - d] : 0;
        __syncthreads();
        ss[t] += add;
        __syncthreads();
    }
    const int nodeoff = boff + ss[t] - v;
    lcur[t] = nodeoff;
    if (t < nn) offsets[lo + t] = nodeoff;
    __syncthreads();

    for (int g = t; g < T; g += 256) {
        int loc = 0, hic = nc - 1;
        while (loc < hic) {
            const int mid = (loc + hic + 1) >> 1;
            if (cum[mid] <= g) loc = mid; else hic = mid - 1;
        }
        const int2 e = stage[s0[loc] + (g - cum[loc])];
        const int slot = atomicAdd(&lcur[e.y - lo], 1);
        csr_src[slot] = e.x;
    }
}

// ---------------------------------------------------------------------------
// aggregate (round-10 exact): one wave/node, lane = 2 channels, VALU edge
// loop, unroll 8, NT out/alpha stores.
// ---------------------------------------------------------------------------
__global__ __launch_bounds__(256) void aggregate(
    const int* __restrict__ csr_src, const int* __restrict__ offsets,
    const uint32_t* __restrict__ xpb, const float* __restrict__ attn_self,
    const float* __restrict__ attn_nei, const float* __restrict__ bias,
    float* __restrict__ out, float* __restrict__ alpha_out,
    float* __restrict__ inv_arr, int N, int E)
{
    const int lane = threadIdx.x & 63;
    int node = blockIdx.x * 4 + (threadIdx.x >> 6);
    if (node >= N) return;
    node = __builtin_amdgcn_readfirstlane(node);

    const int hL = lane >> 4;        // head of this lane's 2 channels
    const int c0 = 2 * lane;

    const float asH = attn_self[(size_t)node * 4 + hL];
    const float anH = attn_nei [(size_t)node * 4 + hL];
    const float eS  = __expf(LEAKY(asH + anH));
    float sumE = eS;
    const uint32_t uS = xpb[(size_t)node * 64 + lane];
    float acc0 = eS * bf_lo(uS), acc1 = eS * bf_hi(uS);

    const int off0 = __builtin_amdgcn_readfirstlane(offsets[node]);
    const int deg  = __builtin_amdgcn_readfirstlane(offsets[node + 1]) - off0;
    const int* srcp = csr_src + off0;

    for (int j = 0; j < deg; j += 8) {
        int s[8];
        #pragma unroll
        for (int k = 0; k < 8; ++k) s[k] = srcp[min(j + k, deg - 1)];
        float a[8];
        #pragma unroll
        for (int k = 0; k < 8; ++k) a[k] = attn_nei[(size_t)s[k] * 4 + hL];
        uint32_t u[8];
        #pragma unroll
        for (int k = 0; k < 8; ++k) u[k] = xpb[(size_t)s[k] * 64 + lane];
        #pragma unroll
        for (int k = 0; k < 8; ++k) {
            const float v = (j + k < deg) ? __expf(LEAKY(asH + a[k])) : 0.0f;
            sumE += v;
            acc0 = fmaf(v, bf_lo(u[k]), acc0);
            acc1 = fmaf(v, bf_hi(u[k]), acc1);
        }
    }

    const float inv = 1.0f / sumE;
    union { float2 f; unsigned long long u; } o;
    o.f = make_float2(fmaf(acc0, inv, bias[c0]), fmaf(acc1, inv, bias[c0 + 1]));
    __builtin_nontemporal_store(o.u,
        (unsigned long long*)&out[(size_t)node * 128 + c0]);
    if ((lane & 15) == 0) {
        inv_arr[(size_t)node * 4 + hL] = inv;
        __builtin_nontemporal_store(eS * inv,
            &alpha_out[(size_t)(E + node) * 4 + hL]);
    }
}

// ---------------------------------------------------------------------------
// alpha for the E real edges: nt ei loads + nt alpha stores.
// ---------------------------------------------------------------------------
__global__ __launch_bounds__(256) void alpha_kernel(
    const int* __restrict__ ei, const float* __restrict__ attn_self,
    const float* __restrict__ attn_nei, const float* __restrict__ inv_arr,
    float* __restrict__ alpha_out, int E)
{
    const int i = blockIdx.x * 256 + threadIdx.x;
    if (i >= E) return;
    const i32x2 e2 = __builtin_nontemporal_load((const i32x2*)ei + i);
    const int src = e2.x, tgt = e2.y;
    const float4 as4 = *(const float4*)&attn_self[(size_t)tgt * 4];
    const float4 an4 = *(const float4*)&attn_nei[(size_t)src * 4];
    const float4 iv4 = *(const float4*)&inv_arr[(size_t)tgt * 4];
    f32x4 a;
    a.x = __expf(LEAKY(as4.x + an4.x)) * iv4.x;
    a.y = __expf(LEAKY(as4.y + an4.y)) * iv4.y;
    a.z = __expf(LEAKY(as4.z + an4.z)) * iv4.z;
    a.w = __expf(LEAKY(as4.w + an4.w)) * iv4.w;
    __builtin_nontemporal_store(a, (f32x4*)&alpha_out[(size_t)i * 4]);
}

// ---------------------------------------------------------------------------
extern "C" void kernel_launch(void* const* d_in, const int* in_sizes, int n_in,
                              void* d_out, int out_size, void* d_ws, size_t ws_size,
                              hipStream_t stream)
{
    const float* x    = (const float*)d_in[0];
    const int*   ei   = (const int*)d_in[1];
    const float* W    = (const float*)d_in[2];
    const float* aks  = (const float*)d_in[3];
    const float* akn  = (const float*)d_in[4];
    const float* bias = (const float*)d_in[5];

    const int N  = in_sizes[0] / 128;
    const int E  = in_sizes[1] / 2;
    const int NB = (N + 255) >> 8;
    const int nc = (E + CHUNK - 1) / CHUNK;

    float* out       = (float*)d_out;
    float* alpha_out = out + (size_t)N * 128;
    int2* stage      = (int2*)alpha_out;   // overlays alpha region (see r7 note)

    char* p = (char*)d_ws;
    auto alloc = [&](size_t bytes) {
        char* r = p;
        p += (bytes + 255) & ~(size_t)255;
        return r;
    };
    uint32_t* xpb       = (uint32_t*)alloc((size_t)N * 64 * 4);
    uint32_t* Wp        = (uint32_t*)alloc((size_t)2048 * 16);
    float* attn_self    = (float*)alloc((size_t)N * 4 * 4);
    float* attn_nei     = (float*)alloc((size_t)N * 4 * 4);
    float* inv_arr      = (float*)alloc((size_t)N * 4 * 4);
    int*   offsets      = (int*)alloc((size_t)(N + 1) * 4);
    int*   csr_src      = (int*)alloc((size_t)E * 4);
    int*   bucket_tot   = (int*)alloc((size_t)NB * 4);
    int*   start_table  = (int*)alloc((size_t)nc * (NB + 1) * 4);

    hipMemsetAsync(bucket_tot, 0, (size_t)NB * 4, stream);

    w_prep<<<8, 256, 0, stream>>>(W, Wp);
    gemm_binA<<<nc + (N + 63) / 64, 256, 0, stream>>>(
        x, Wp, aks, akn, xpb, attn_self, attn_nei,
        ei, stage, start_table, bucket_tot, nc, NB, N, E);
    binB<<<NB, 256, 0, stream>>>(stage, start_table, bucket_tot, offsets,
                                 csr_src, nc, NB, N, E);
    aggregate<<<(N + 3) / 4, 256, 0, stream>>>(csr_src, offsets, xpb,
                                               attn_self, attn_nei, bias, out,
                                               alpha_out, inv_arr, N, E);
    alpha_kernel<<<(E + 255) / 256, 256, 0, stream>>>(ei, attn_self, attn_nei,
                                                      inv_arr, alpha_out, E);
}

// Round 13
// 182.391 us; speedup vs baseline: 3.9924x; 1.0563x over previous
//
#include <hip/hip_runtime.h>
#include <hip/hip_bf16.h>
#include <math.h>

#define LEAKY(x) ((x) >= 0.0f ? (x) : 0.2f * (x))
#define CHUNK 8192

typedef __attribute__((ext_vector_type(8))) short short8;
typedef __attribute__((ext_vector_type(4))) float f32x4;
typedef __attribute__((ext_vector_type(2))) int i32x2;

__device__ __forceinline__ float bf_lo(uint32_t u) { return __uint_as_float(u << 16); }
__device__ __forceinline__ float bf_hi(uint32_t u) { return __uint_as_float(u & 0xffff0000u); }
__device__ __forceinline__ uint32_t pack2(float a, float b) {
    __hip_bfloat162 h = __float22bfloat162_rn(make_float2(a, b));
    return *reinterpret_cast<uint32_t*>(&h);
}

// ---------------------------------------------------------------------------
// K1 (fused): blocks [0, nc): binA edge binning (per-chunk LDS hist/scan ->
// bucket-grouped stage + start_table; NO global atomics). Blocks [nc, nc+8):
// w_prep (pack W into bf16 MFMA B-fragment order).
// ---------------------------------------------------------------------------
__global__ __launch_bounds__(256) void binA_wprep(
    const int* __restrict__ ei, int2* __restrict__ stage,
    int* __restrict__ start_table, const float* __restrict__ W,
    uint32_t* __restrict__ Wp, int nc, int NB, int E)
{
    __shared__ int lh[512], lex[512], ss[256];
    const int t = threadIdx.x;

    if (blockIdx.x >= nc) {                   // ---- w_prep part ----
        const int slot = (blockIdx.x - nc) * 256 + t;
        if (slot >= 2048) return;
        const int kb = slot >> 9;
        const int cb = (slot >> 6) & 7;
        const int l  = slot & 63;
        const int k0 = kb * 32 + (l >> 4) * 8;
        const int col = cb * 16 + (l & 15);
        uint32_t u[4];
        #pragma unroll
        for (int p = 0; p < 4; ++p) {
            const float a = W[(size_t)(k0 + 2 * p) * 128 + col];
            const float b = W[(size_t)(k0 + 2 * p + 1) * 128 + col];
            u[p] = pack2(a, b);
        }
        *(uint4*)&Wp[(size_t)slot * 4] = make_uint4(u[0], u[1], u[2], u[3]);
        return;
    }

    // ---- binA part ----
    const int base = blockIdx.x * CHUNK;
    const int end  = min(E, base + CHUNK);

    for (int i = t; i < 512; i += 256) lh[i] = 0;
    __syncthreads();
    for (int i = base + t; i < end; i += 256)
        atomicAdd(&lh[((const int2*)ei)[i].y >> 8], 1);
    __syncthreads();

    const int v0 = lh[2 * t], v1 = lh[2 * t + 1];
    ss[t] = v0 + v1;
    __syncthreads();
    for (int d = 1; d < 256; d <<= 1) {
        const int add = (t >= d) ? ss[t - d] : 0;
        __syncthreads();
        ss[t] += add;
        __syncthreads();
    }
    const int ex = ss[t] - v0 - v1;
    lex[2 * t] = ex;
    lex[2 * t + 1] = ex + v0;
    __syncthreads();

    const size_t cbase = (size_t)blockIdx.x * (NB + 1);
    for (int b = t; b <= NB; b += 256) start_table[cbase + b] = base + lex[b];
    __syncthreads();

    for (int i = base + t; i < end; i += 256) {
        const int2 e2 = ((const int2*)ei)[i];
        const int slot = atomicAdd(&lex[e2.y >> 8], 1);
        stage[base + slot] = e2;
    }
}

// ---------------------------------------------------------------------------
// K2 (fused): blocks [0, NB): binB (CSR finalize, depends only on binA);
// blocks [NB, ...): MFMA GEMM (depends only on w_prep). binB's gather/LDS
// work hides under the GEMM's MFMA + streaming. Shared LDS overlay.
// bucket offset computed analytically: boff = sum_c(start_table[c][b]-c*CHUNK).
// ---------------------------------------------------------------------------
__global__ __launch_bounds__(256) void gemm_binB(
    const float* __restrict__ x, const uint32_t* __restrict__ Wp,
    const float* __restrict__ aks, const float* __restrict__ akn,
    uint32_t* __restrict__ xpb, float* __restrict__ attn_self,
    float* __restrict__ attn_nei, const int2* __restrict__ stage,
    const int* __restrict__ start_table, int* __restrict__ offsets,
    int* __restrict__ csr_src, int nc, int NB, int N, int E)
{
    __shared__ __align__(16) char smem[16896];   // max(gemm 16896, binB 6148)
    const int t = threadIdx.x;

    if (blockIdx.x < NB) {                    // ---- binB part ----
        int* s0   = (int*)smem;               // [256]
        int* cum  = s0 + 256;                 // [257]
        int* ss   = cum + 257;                // [256]
        int* lcnt = ss + 256;                 // [256]
        int* lcur = lcnt + 256;               // [256]
        int* red  = lcur + 256;               // [256]
        const int b  = blockIdx.x;
        const int lo = b << 8;
        const int nn = min(N, lo + 256) - lo;

        int part = 0, len = 0;
        if (t < nc) {
            const size_t cb = (size_t)t * (NB + 1);
            const int a0 = start_table[cb + b];
            s0[t] = a0;
            len   = start_table[cb + b + 1] - a0;
            part  = a0 - t * CHUNK;           // prefix of chunk t's buckets < b
        }
        ss[t] = len;
        lcnt[t] = 0;
        red[t] = part;
        if (t == 0 && b == 0) offsets[N] = E;
        __syncthreads();
        for (int d = 128; d > 0; d >>= 1) {
            if (t < d) red[t] += red[t + d];
            __syncthreads();
        }
        const int boff = red[0];
        for (int d = 1; d < 256; d <<= 1) {
            const int add = (t >= d) ? ss[t - d] : 0;
            __syncthreads();
            ss[t] += add;
            __syncthreads();
        }
        if (t == 0) cum[0] = 0;
        cum[t + 1] = ss[t];
        __syncthreads();
        const int T = cum[nc];

        for (int g = t; g < T; g += 256) {
            int loc = 0, hic = nc - 1;
            while (loc < hic) {
                const int mid = (loc + hic + 1) >> 1;
                if (cum[mid] <= g) loc = mid; else hic = mid - 1;
            }
            const int2 e = stage[s0[loc] + (g - cum[loc])];
            atomicAdd(&lcnt[e.y - lo], 1);
        }
        __syncthreads();

        const int v = lcnt[t];
        ss[t] = v;
        __syncthreads();
        for (int d = 1; d < 256; d <<= 1) {
            const int add = (t >= d) ? ss[t - d] : 0;
            __syncthreads();
            ss[t] += add;
            __syncthreads();
        }
        const int nodeoff = boff + ss[t] - v;
        lcur[t] = nodeoff;
        if (t < nn) offsets[lo + t] = nodeoff;
        __syncthreads();

        for (int g = t; g < T; g += 256) {
            int loc = 0, hic = nc - 1;
            while (loc < hic) {
                const int mid = (loc + hic + 1) >> 1;
                if (cum[mid] <= g) loc = mid; else hic = mid - 1;
            }
            const int2 e = stage[s0[loc] + (g - cum[loc])];
            const int slot = atomicAdd(&lcur[e.y - lo], 1);
            csr_src[slot] = e.x;
        }
        return;
    }

    // ---- GEMM part ----
    ushort (*xs)[132] = (ushort(*)[132])smem;     // bf16 LDS: 16.9 KB
    const int blk = blockIdx.x - NB;
    const int w  = t >> 6;
    const int l  = t & 63;
    const int nb = blk * 64;

    const int row  = nb + w * 16 + (l & 15);
    const int rowc = min(row, N - 1);
    const int kg   = (l >> 4) * 8;
    const float* xrow = x + (size_t)rowc * 128 + kg;

    f32x4 acc[8] = {};
    #pragma unroll
    for (int kb = 0; kb < 4; ++kb) {
        const f32x4 x0 = __builtin_nontemporal_load((const f32x4*)(xrow + kb * 32));
        const f32x4 x1 = __builtin_nontemporal_load((const f32x4*)(xrow + kb * 32 + 4));
        union { short8 s; uint32_t u[4]; } A;
        A.u[0] = pack2(x0.x, x0.y); A.u[1] = pack2(x0.z, x0.w);
        A.u[2] = pack2(x1.x, x1.y); A.u[3] = pack2(x1.z, x1.w);
        #pragma unroll
        for (int cb = 0; cb < 8; ++cb) {
            union { short8 s; uint4 u; } B;
            B.u = *(const uint4*)&Wp[(((size_t)(kb * 8 + cb)) * 64 + l) * 4];
            acc[cb] = __builtin_amdgcn_mfma_f32_16x16x32_bf16(A.s, B.s, acc[cb], 0, 0, 0);
        }
    }

    // D -> LDS as bf16 (RNE): row = w*16+(l>>4)*4+r, col = cb*16+(l&15)
    const int r0 = (l >> 4) * 4;
    const int cl = l & 15;
    #pragma unroll
    for (int cb = 0; cb < 8; ++cb)
        #pragma unroll
        for (int r = 0; r < 4; ++r)
            xs[w * 16 + r0 + r][cb * 16 + cl] =
                (ushort)(pack2(acc[cb][r], 0.0f) & 0xffffu);
    __syncthreads();

    // repack 64 nodes x 64 uints (pairs are adjacent in LDS), coalesced
    #pragma unroll
    for (int i = 0; i < 16; ++i) {
        const int idx = t + i * 256;           // 0..4095
        const int n = idx >> 6, q = idx & 63;
        const int gn = nb + n;
        if (gn < N)
            xpb[(size_t)gn * 64 + q] = *(const uint32_t*)&xs[n][2 * q];
    }

    // attn from bf16 LDS (wave-major: lane = node, wave = head)
    {
        const int n = t & 63, h = t >> 6;
        const int gn = nb + n;
        if (gn < N) {
            float sv = 0.0f, sn = 0.0f;
            #pragma unroll
            for (int c = 0; c < 32; ++c) {
                const float v = __uint_as_float((uint32_t)xs[n][h * 32 + c] << 16);
                sv = fmaf(v, aks[c * 4 + h], sv);
                sn = fmaf(v, akn[c * 4 + h], sn);
            }
            attn_self[(size_t)gn * 4 + h] = sv;
            attn_nei [(size_t)gn * 4 + h] = sn;
        }
    }
}

// ---------------------------------------------------------------------------
// aggregate (round-10/12 exact): one wave/node, lane = 2 channels, VALU edge
// loop, unroll 8, NT out/alpha stores. Established floor ~78 us.
// ---------------------------------------------------------------------------
__global__ __launch_bounds__(256) void aggregate(
    const int* __restrict__ csr_src, const int* __restrict__ offsets,
    const uint32_t* __restrict__ xpb, const float* __restrict__ attn_self,
    const float* __restrict__ attn_nei, const float* __restrict__ bias,
    float* __restrict__ out, float* __restrict__ alpha_out,
    float* __restrict__ inv_arr, int N, int E)
{
    const int lane = threadIdx.x & 63;
    int node = blockIdx.x * 4 + (threadIdx.x >> 6);
    if (node >= N) return;
    node = __builtin_amdgcn_readfirstlane(node);

    const int hL = lane >> 4;        // head of this lane's 2 channels
    const int c0 = 2 * lane;

    const float asH = attn_self[(size_t)node * 4 + hL];
    const float anH = attn_nei [(size_t)node * 4 + hL];
    const float eS  = __expf(LEAKY(asH + anH));
    float sumE = eS;
    const uint32_t uS = xpb[(size_t)node * 64 + lane];
    float acc0 = eS * bf_lo(uS), acc1 = eS * bf_hi(uS);

    const int off0 = __builtin_amdgcn_readfirstlane(offsets[node]);
    const int deg  = __builtin_amdgcn_readfirstlane(offsets[node + 1]) - off0;
    const int* srcp = csr_src + off0;

    for (int j = 0; j < deg; j += 8) {
        int s[8];
        #pragma unroll
        for (int k = 0; k < 8; ++k) s[k] = srcp[min(j + k, deg - 1)];
        float a[8];
        #pragma unroll
        for (int k = 0; k < 8; ++k) a[k] = attn_nei[(size_t)s[k] * 4 + hL];
        uint32_t u[8];
        #pragma unroll
        for (int k = 0; k < 8; ++k) u[k] = xpb[(size_t)s[k] * 64 + lane];
        #pragma unroll
        for (int k = 0; k < 8; ++k) {
            const float v = (j + k < deg) ? __expf(LEAKY(asH + a[k])) : 0.0f;
            sumE += v;
            acc0 = fmaf(v, bf_lo(u[k]), acc0);
            acc1 = fmaf(v, bf_hi(u[k]), acc1);
        }
    }

    const float inv = 1.0f / sumE;
    union { float2 f; unsigned long long u; } o;
    o.f = make_float2(fmaf(acc0, inv, bias[c0]), fmaf(acc1, inv, bias[c0 + 1]));
    __builtin_nontemporal_store(o.u,
        (unsigned long long*)&out[(size_t)node * 128 + c0]);
    if ((lane & 15) == 0) {
        inv_arr[(size_t)node * 4 + hL] = inv;
        __builtin_nontemporal_store(eS * inv,
            &alpha_out[(size_t)(E + node) * 4 + hL]);
    }
}

// ---------------------------------------------------------------------------
// alpha for the E real edges: nt ei loads + nt alpha stores.
// ---------------------------------------------------------------------------
__global__ __launch_bounds__(256) void alpha_kernel(
    const int* __restrict__ ei, const float* __restrict__ attn_self,
    const float* __restrict__ attn_nei, const float* __restrict__ inv_arr,
    float* __restrict__ alpha_out, int E)
{
    const int i = blockIdx.x * 256 + threadIdx.x;
    if (i >= E) return;
    const i32x2 e2 = __builtin_nontemporal_load((const i32x2*)ei + i);
    const int src = e2.x, tgt = e2.y;
    const float4 as4 = *(const float4*)&attn_self[(size_t)tgt * 4];
    const float4 an4 = *(const float4*)&attn_nei[(size_t)src * 4];
    const float4 iv4 = *(const float4*)&inv_arr[(size_t)tgt * 4];
    f32x4 a;
    a.x = __expf(LEAKY(as4.x + an4.x)) * iv4.x;
    a.y = __expf(LEAKY(as4.y + an4.y)) * iv4.y;
    a.z = __expf(LEAKY(as4.z + an4.z)) * iv4.z;
    a.w = __expf(LEAKY(as4.w + an4.w)) * iv4.w;
    __builtin_nontemporal_store(a, (f32x4*)&alpha_out[(size_t)i * 4]);
}

// ---------------------------------------------------------------------------
extern "C" void kernel_launch(void* const* d_in, const int* in_sizes, int n_in,
                              void* d_out, int out_size, void* d_ws, size_t ws_size,
                              hipStream_t stream)
{
    const float* x    = (const float*)d_in[0];
    const int*   ei   = (const int*)d_in[1];
    const float* W    = (const float*)d_in[2];
    const float* aks  = (const float*)d_in[3];
    const float* akn  = (const float*)d_in[4];
    const float* bias = (const float*)d_in[5];

    const int N  = in_sizes[0] / 128;
    const int E  = in_sizes[1] / 2;
    const int NB = (N + 255) >> 8;
    const int nc = (E + CHUNK - 1) / CHUNK;

    float* out       = (float*)d_out;
    float* alpha_out = out + (size_t)N * 128;
    int2* stage      = (int2*)alpha_out;   // overlays alpha region (see r7 note)

    char* p = (char*)d_ws;
    auto alloc = [&](size_t bytes) {
        char* r = p;
        p += (bytes + 255) & ~(size_t)255;
        return r;
    };
    uint32_t* xpb       = (uint32_t*)alloc((size_t)N * 64 * 4);
    uint32_t* Wp        = (uint32_t*)alloc((size_t)2048 * 16);
    float* attn_self    = (float*)alloc((size_t)N * 4 * 4);
    float* attn_nei     = (float*)alloc((size_t)N * 4 * 4);
    float* inv_arr      = (float*)alloc((size_t)N * 4 * 4);
    int*   offsets      = (int*)alloc((size_t)(N + 1) * 4);
    int*   csr_src      = (int*)alloc((size_t)E * 4);
    int*   start_table  = (int*)alloc((size_t)nc * (NB + 1) * 4);

    binA_wprep<<<nc + 8, 256, 0, stream>>>(ei, stage, start_table, W, Wp,
                                           nc, NB, E);
    gemm_binB<<<NB + (N + 63) / 64, 256, 0, stream>>>(
        x, Wp, aks, akn, xpb, attn_self, attn_nei,
        stage, start_table, offsets, csr_src, nc, NB, N, E);
    aggregate<<<(N + 3) / 4, 256, 0, stream>>>(csr_src, offsets, xpb,
                                               attn_self, attn_nei, bias, out,
                                               alpha_out, inv_arr, N, E);
    alpha_kernel<<<(E + 255) / 256, 256, 0, stream>>>(ei, attn_self, attn_nei,
                                                      inv_arr, alpha_out, E);
}

// Round 14
// 181.161 us; speedup vs baseline: 4.0195x; 1.0068x over previous
//
#include <hip/hip_runtime.h>
#include <hip/hip_bf16.h>
#include <math.h>

#define LEAKY(x) ((x) >= 0.0f ? (x) : 0.2f * (x))
#define CHUNK 8192

typedef __attribute__((ext_vector_type(8))) short short8;
typedef __attribute__((ext_vector_type(4))) float f32x4;
typedef __attribute__((ext_vector_type(2))) int i32x2;
typedef __attribute__((ext_vector_type(4))) int i32x4;

__device__ __forceinline__ float bf_lo(uint32_t u) { return __uint_as_float(u << 16); }
__device__ __forceinline__ float bf_hi(uint32_t u) { return __uint_as_float(u & 0xffff0000u); }
__device__ __forceinline__ uint32_t pack2(float a, float b) {
    __hip_bfloat162 h = __float22bfloat162_rn(make_float2(a, b));
    return *reinterpret_cast<uint32_t*>(&h);
}

// ---------------------------------------------------------------------------
// K1 (fused): blocks [0, nc): binA edge binning -> PACKED 4 B stage entries
// ((src<<8)|(tgt&255); src<2^24, bucket implies tgt high bits).
// Blocks [nc, nc+8): w_prep (pack W into bf16 MFMA B-fragment order).
// ---------------------------------------------------------------------------
__global__ __launch_bounds__(256) void binA_wprep(
    const int* __restrict__ ei, uint32_t* __restrict__ stage,
    int* __restrict__ start_table, const float* __restrict__ W,
    uint32_t* __restrict__ Wp, int nc, int NB, int E)
{
    __shared__ int lh[512], lex[512], ss[256];
    const int t = threadIdx.x;

    if (blockIdx.x >= nc) {                   // ---- w_prep part ----
        const int slot = (blockIdx.x - nc) * 256 + t;
        if (slot >= 2048) return;
        const int kb = slot >> 9;
        const int cb = (slot >> 6) & 7;
        const int l  = slot & 63;
        const int k0 = kb * 32 + (l >> 4) * 8;
        const int col = cb * 16 + (l & 15);
        uint32_t u[4];
        #pragma unroll
        for (int p = 0; p < 4; ++p) {
            const float a = W[(size_t)(k0 + 2 * p) * 128 + col];
            const float b = W[(size_t)(k0 + 2 * p + 1) * 128 + col];
            u[p] = pack2(a, b);
        }
        *(uint4*)&Wp[(size_t)slot * 4] = make_uint4(u[0], u[1], u[2], u[3]);
        return;
    }

    // ---- binA part ----
    const int base = blockIdx.x * CHUNK;
    const int end  = min(E, base + CHUNK);

    for (int i = t; i < 512; i += 256) lh[i] = 0;
    __syncthreads();
    for (int i = base + t; i < end; i += 256)
        atomicAdd(&lh[((const int2*)ei)[i].y >> 8], 1);
    __syncthreads();

    const int v0 = lh[2 * t], v1 = lh[2 * t + 1];
    ss[t] = v0 + v1;
    __syncthreads();
    for (int d = 1; d < 256; d <<= 1) {
        const int add = (t >= d) ? ss[t - d] : 0;
        __syncthreads();
        ss[t] += add;
        __syncthreads();
    }
    const int ex = ss[t] - v0 - v1;
    lex[2 * t] = ex;
    lex[2 * t + 1] = ex + v0;
    __syncthreads();

    const size_t cbase = (size_t)blockIdx.x * (NB + 1);
    for (int b = t; b <= NB; b += 256) start_table[cbase + b] = base + lex[b];
    __syncthreads();

    for (int i = base + t; i < end; i += 256) {
        const int2 e2 = ((const int2*)ei)[i];
        const int slot = atomicAdd(&lex[e2.y >> 8], 1);
        stage[base + slot] = ((uint32_t)e2.x << 8) | ((uint32_t)e2.y & 255u);
    }
}

// ---------------------------------------------------------------------------
// K2 (fused): blocks [0, NB): binB (CSR finalize from packed stage);
// blocks [NB, ...): MFMA GEMM. binB hides under the GEMM stream.
// boff computed analytically: sum_c(start_table[c][b]-c*CHUNK).
// ---------------------------------------------------------------------------
__global__ __launch_bounds__(256) void gemm_binB(
    const float* __restrict__ x, const uint32_t* __restrict__ Wp,
    const float* __restrict__ aks, const float* __restrict__ akn,
    uint32_t* __restrict__ xpb, float* __restrict__ attn_self,
    float* __restrict__ attn_nei, const uint32_t* __restrict__ stage,
    const int* __restrict__ start_table, int* __restrict__ offsets,
    int* __restrict__ csr_src, int nc, int NB, int N, int E)
{
    __shared__ __align__(16) char smem[16896];   // max(gemm 16896, binB 6148)
    const int t = threadIdx.x;

    if (blockIdx.x < NB) {                    // ---- binB part ----
        int* s0   = (int*)smem;               // [256]
        int* cum  = s0 + 256;                 // [257]
        int* ss   = cum + 257;                // [256]
        int* lcnt = ss + 256;                 // [256]
        int* lcur = lcnt + 256;               // [256]
        int* red  = lcur + 256;               // [256]
        const int b  = blockIdx.x;
        const int lo = b << 8;
        const int nn = min(N, lo + 256) - lo;

        int part = 0, len = 0;
        if (t < nc) {
            const size_t cb = (size_t)t * (NB + 1);
            const int a0 = start_table[cb + b];
            s0[t] = a0;
            len   = start_table[cb + b + 1] - a0;
            part  = a0 - t * CHUNK;
        }
        ss[t] = len;
        lcnt[t] = 0;
        red[t] = part;
        if (t == 0 && b == 0) offsets[N] = E;
        __syncthreads();
        for (int d = 128; d > 0; d >>= 1) {
            if (t < d) red[t] += red[t + d];
            __syncthreads();
        }
        const int boff = red[0];
        for (int d = 1; d < 256; d <<= 1) {
            const int add = (t >= d) ? ss[t - d] : 0;
            __syncthreads();
            ss[t] += add;
            __syncthreads();
        }
        if (t == 0) cum[0] = 0;
        cum[t + 1] = ss[t];
        __syncthreads();
        const int T = cum[nc];

        for (int g = t; g < T; g += 256) {
            int loc = 0, hic = nc - 1;
            while (loc < hic) {
                const int mid = (loc + hic + 1) >> 1;
                if (cum[mid] <= g) loc = mid; else hic = mid - 1;
            }
            const uint32_t e = stage[s0[loc] + (g - cum[loc])];
            atomicAdd(&lcnt[e & 255u], 1);
        }
        __syncthreads();

        const int v = lcnt[t];
        ss[t] = v;
        __syncthreads();
        for (int d = 1; d < 256; d <<= 1) {
            const int add = (t >= d) ? ss[t - d] : 0;
            __syncthreads();
            ss[t] += add;
            __syncthreads();
        }
        const int nodeoff = boff + ss[t] - v;
        lcur[t] = nodeoff;
        if (t < nn) offsets[lo + t] = nodeoff;
        __syncthreads();

        for (int g = t; g < T; g += 256) {
            int loc = 0, hic = nc - 1;
            while (loc < hic) {
                const int mid = (loc + hic + 1) >> 1;
                if (cum[mid] <= g) loc = mid; else hic = mid - 1;
            }
            const uint32_t e = stage[s0[loc] + (g - cum[loc])];
            const int slot = atomicAdd(&lcur[e & 255u], 1);
            csr_src[slot] = (int)(e >> 8);
        }
        return;
    }

    // ---- GEMM part ----
    ushort (*xs)[132] = (ushort(*)[132])smem;     // bf16 LDS: 16.9 KB
    const int blk = blockIdx.x - NB;
    const int w  = t >> 6;
    const int l  = t & 63;
    const int nb = blk * 64;

    const int row  = nb + w * 16 + (l & 15);
    const int rowc = min(row, N - 1);
    const int kg   = (l >> 4) * 8;
    const float* xrow = x + (size_t)rowc * 128 + kg;

    f32x4 acc[8] = {};
    #pragma unroll
    for (int kb = 0; kb < 4; ++kb) {
        const f32x4 x0 = __builtin_nontemporal_load((const f32x4*)(xrow + kb * 32));
        const f32x4 x1 = __builtin_nontemporal_load((const f32x4*)(xrow + kb * 32 + 4));
        union { short8 s; uint32_t u[4]; } A;
        A.u[0] = pack2(x0.x, x0.y); A.u[1] = pack2(x0.z, x0.w);
        A.u[2] = pack2(x1.x, x1.y); A.u[3] = pack2(x1.z, x1.w);
        #pragma unroll
        for (int cb = 0; cb < 8; ++cb) {
            union { short8 s; uint4 u; } B;
            B.u = *(const uint4*)&Wp[(((size_t)(kb * 8 + cb)) * 64 + l) * 4];
            acc[cb] = __builtin_amdgcn_mfma_f32_16x16x32_bf16(A.s, B.s, acc[cb], 0, 0, 0);
        }
    }

    const int r0 = (l >> 4) * 4;
    const int cl = l & 15;
    #pragma unroll
    for (int cb = 0; cb < 8; ++cb)
        #pragma unroll
        for (int r = 0; r < 4; ++r)
            xs[w * 16 + r0 + r][cb * 16 + cl] =
                (ushort)(pack2(acc[cb][r], 0.0f) & 0xffffu);
    __syncthreads();

    #pragma unroll
    for (int i = 0; i < 16; ++i) {
        const int idx = t + i * 256;           // 0..4095
        const int n = idx >> 6, q = idx & 63;
        const int gn = nb + n;
        if (gn < N)
            xpb[(size_t)gn * 64 + q] = *(const uint32_t*)&xs[n][2 * q];
    }

    {
        const int n = t & 63, h = t >> 6;
        const int gn = nb + n;
        if (gn < N) {
            float sv = 0.0f, sn = 0.0f;
            #pragma unroll
            for (int c = 0; c < 32; ++c) {
                const float v = __uint_as_float((uint32_t)xs[n][h * 32 + c] << 16);
                sv = fmaf(v, aks[c * 4 + h], sv);
                sn = fmaf(v, akn[c * 4 + h], sn);
            }
            attn_self[(size_t)gn * 4 + h] = sv;
            attn_nei [(size_t)gn * 4 + h] = sn;
        }
    }
}

// ---------------------------------------------------------------------------
// aggregate (round-10/12 exact): one wave/node, lane = 2 channels, VALU edge
// loop, unroll 8, NT out/alpha stores. Established floor ~78 us.
// ---------------------------------------------------------------------------
__global__ __launch_bounds__(256) void aggregate(
    const int* __restrict__ csr_src, const int* __restrict__ offsets,
    const uint32_t* __restrict__ xpb, const float* __restrict__ attn_self,
    const float* __restrict__ attn_nei, const float* __restrict__ bias,
    float* __restrict__ out, float* __restrict__ alpha_out,
    float* __restrict__ inv_arr, int N, int E)
{
    const int lane = threadIdx.x & 63;
    int node = blockIdx.x * 4 + (threadIdx.x >> 6);
    if (node >= N) return;
    node = __builtin_amdgcn_readfirstlane(node);

    const int hL = lane >> 4;        // head of this lane's 2 channels
    const int c0 = 2 * lane;

    const float asH = attn_self[(size_t)node * 4 + hL];
    const float anH = attn_nei [(size_t)node * 4 + hL];
    const float eS  = __expf(LEAKY(asH + anH));
    float sumE = eS;
    const uint32_t uS = xpb[(size_t)node * 64 + lane];
    float acc0 = eS * bf_lo(uS), acc1 = eS * bf_hi(uS);

    const int off0 = __builtin_amdgcn_readfirstlane(offsets[node]);
    const int deg  = __builtin_amdgcn_readfirstlane(offsets[node + 1]) - off0;
    const int* srcp = csr_src + off0;

    for (int j = 0; j < deg; j += 8) {
        int s[8];
        #pragma unroll
        for (int k = 0; k < 8; ++k) s[k] = srcp[min(j + k, deg - 1)];
        float a[8];
        #pragma unroll
        for (int k = 0; k < 8; ++k) a[k] = attn_nei[(size_t)s[k] * 4 + hL];
        uint32_t u[8];
        #pragma unroll
        for (int k = 0; k < 8; ++k) u[k] = xpb[(size_t)s[k] * 64 + lane];
        #pragma unroll
        for (int k = 0; k < 8; ++k) {
            const float v = (j + k < deg) ? __expf(LEAKY(asH + a[k])) : 0.0f;
            sumE += v;
            acc0 = fmaf(v, bf_lo(u[k]), acc0);
            acc1 = fmaf(v, bf_hi(u[k]), acc1);
        }
    }

    const float inv = 1.0f / sumE;
    union { float2 f; unsigned long long u; } o;
    o.f = make_float2(fmaf(acc0, inv, bias[c0]), fmaf(acc1, inv, bias[c0 + 1]));
    __builtin_nontemporal_store(o.u,
        (unsigned long long*)&out[(size_t)node * 128 + c0]);
    if ((lane & 15) == 0) {
        inv_arr[(size_t)node * 4 + hL] = inv;
        __builtin_nontemporal_store(eS * inv,
            &alpha_out[(size_t)(E + node) * 4 + hL]);
    }
}

// ---------------------------------------------------------------------------
// alpha for the E real edges: 2 edges/thread, nt int4 ei loads + nt stores.
// ---------------------------------------------------------------------------
__global__ __launch_bounds__(256) void alpha_kernel(
    const int* __restrict__ ei, const float* __restrict__ attn_self,
    const float* __restrict__ attn_nei, const float* __restrict__ inv_arr,
    float* __restrict__ alpha_out, int E)
{
    const int i0 = (blockIdx.x * 256 + threadIdx.x) * 2;
    if (i0 >= E) return;
    const int i1 = min(i0 + 1, E - 1);
    i32x4 e4;
    if (i0 + 1 < E) {
        e4 = __builtin_nontemporal_load((const i32x4*)(ei + 2 * (size_t)i0));
    } else {
        const i32x2 ea = __builtin_nontemporal_load((const i32x2*)(ei + 2 * (size_t)i0));
        e4.x = ea.x; e4.y = ea.y; e4.z = ea.x; e4.w = ea.y;
    }
    #pragma unroll
    for (int k = 0; k < 2; ++k) {
        const int i   = k ? i1 : i0;
        const int src = k ? e4.z : e4.x;
        const int tgt = k ? e4.w : e4.y;
        const float4 as4 = *(const float4*)&attn_self[(size_t)tgt * 4];
        const float4 an4 = *(const float4*)&attn_nei[(size_t)src * 4];
        const float4 iv4 = *(const float4*)&inv_arr[(size_t)tgt * 4];
        f32x4 a;
        a.x = __expf(LEAKY(as4.x + an4.x)) * iv4.x;
        a.y = __expf(LEAKY(as4.y + an4.y)) * iv4.y;
        a.z = __expf(LEAKY(as4.z + an4.z)) * iv4.z;
        a.w = __expf(LEAKY(as4.w + an4.w)) * iv4.w;
        __builtin_nontemporal_store(a, (f32x4*)&alpha_out[(size_t)i * 4]);
    }
}

// ---------------------------------------------------------------------------
extern "C" void kernel_launch(void* const* d_in, const int* in_sizes, int n_in,
                              void* d_out, int out_size, void* d_ws, size_t ws_size,
                              hipStream_t stream)
{
    const float* x    = (const float*)d_in[0];
    const int*   ei   = (const int*)d_in[1];
    const float* W    = (const float*)d_in[2];
    const float* aks  = (const float*)d_in[3];
    const float* akn  = (const float*)d_in[4];
    const float* bias = (const float*)d_in[5];

    const int N  = in_sizes[0] / 128;
    const int E  = in_sizes[1] / 2;
    const int NB = (N + 255) >> 8;
    const int nc = (E + CHUNK - 1) / CHUNK;

    float* out       = (float*)d_out;
    float* alpha_out = out + (size_t)N * 128;
    uint32_t* stage  = (uint32_t*)alpha_out;  // overlays alpha region (r7 note)

    char* p = (char*)d_ws;
    auto alloc = [&](size_t bytes) {
        char* r = p;
        p += (bytes + 255) & ~(size_t)255;
        return r;
    };
    uint32_t* xpb       = (uint32_t*)alloc((size_t)N * 64 * 4);
    uint32_t* Wp        = (uint32_t*)alloc((size_t)2048 * 16);
    float* attn_self    = (float*)alloc((size_t)N * 4 * 4);
    float* attn_nei     = (float*)alloc((size_t)N * 4 * 4);
    float* inv_arr      = (float*)alloc((size_t)N * 4 * 4);
    int*   offsets      = (int*)alloc((size_t)(N + 1) * 4);
    int*   csr_src      = (int*)alloc((size_t)E * 4);
    int*   start_table  = (int*)alloc((size_t)nc * (NB + 1) * 4);

    binA_wprep<<<nc + 8, 256, 0, stream>>>(ei, stage, start_table, W, Wp,
                                           nc, NB, E);
    gemm_binB<<<NB + (N + 63) / 64, 256, 0, stream>>>(
        x, Wp, aks, akn, xpb, attn_self, attn_nei,
        stage, start_table, offsets, csr_src, nc, NB, N, E);
    aggregate<<<(N + 3) / 4, 256, 0, stream>>>(csr_src, offsets, xpb,
                                               attn_self, attn_nei, bias, out,
                                               alpha_out, inv_arr, N, E);
    alpha_kernel<<<((E + 1) / 2 + 255) / 256, 256, 0, stream>>>(
        ei, attn_self, attn_nei, inv_arr, alpha_out, E);
}

// Round 15
// 178.354 us; speedup vs baseline: 4.0828x; 1.0157x over previous
//
#include <hip/hip_runtime.h>
#include <hip/hip_bf16.h>
#include <math.h>

#define LEAKY(x) ((x) >= 0.0f ? (x) : 0.2f * (x))
#define CHUNK 8192

typedef __attribute__((ext_vector_type(8))) short short8;
typedef __attribute__((ext_vector_type(4))) float f32x4;
typedef __attribute__((ext_vector_type(2))) int i32x2;
typedef __attribute__((ext_vector_type(4))) int i32x4;

__device__ __forceinline__ float bf_lo(uint32_t u) { return __uint_as_float(u << 16); }
__device__ __forceinline__ float bf_hi(uint32_t u) { return __uint_as_float(u & 0xffff0000u); }
__device__ __forceinline__ uint32_t pack2(float a, float b) {
    __hip_bfloat162 h = __float22bfloat162_rn(make_float2(a, b));
    return *reinterpret_cast<uint32_t*>(&h);
}

// Buckets of 128 nodes (bucket = tgt >> 7): 2x binB parallelism vs 256.
// ---------------------------------------------------------------------------
// K1 (fused): blocks [0, nc): binA edge binning -> packed 4 B stage entries
// ((src<<8)|(tgt&127)). Blocks [nc, nc+8): w_prep.
// ---------------------------------------------------------------------------
__global__ __launch_bounds__(256) void binA_wprep(
    const int* __restrict__ ei, uint32_t* __restrict__ stage,
    int* __restrict__ start_table, const float* __restrict__ W,
    uint32_t* __restrict__ Wp, int nc, int NB, int E)
{
    __shared__ int lh[1024], lex[1024], ss[256];
    const int t = threadIdx.x;

    if (blockIdx.x >= nc) {                   // ---- w_prep part ----
        const int slot = (blockIdx.x - nc) * 256 + t;
        if (slot >= 2048) return;
        const int kb = slot >> 9;
        const int cb = (slot >> 6) & 7;
        const int l  = slot & 63;
        const int k0 = kb * 32 + (l >> 4) * 8;
        const int col = cb * 16 + (l & 15);
        uint32_t u[4];
        #pragma unroll
        for (int p = 0; p < 4; ++p) {
            const float a = W[(size_t)(k0 + 2 * p) * 128 + col];
            const float b = W[(size_t)(k0 + 2 * p + 1) * 128 + col];
            u[p] = pack2(a, b);
        }
        *(uint4*)&Wp[(size_t)slot * 4] = make_uint4(u[0], u[1], u[2], u[3]);
        return;
    }

    // ---- binA part ----
    const int base = blockIdx.x * CHUNK;
    const int end  = min(E, base + CHUNK);

    for (int i = t; i < 1024; i += 256) lh[i] = 0;
    __syncthreads();
    for (int i = base + t; i < end; i += 256)
        atomicAdd(&lh[((const int2*)ei)[i].y >> 7], 1);
    __syncthreads();

    // exclusive scan of lh[0..1024) -> lex (4 per thread)
    int v[4];
    #pragma unroll
    for (int k = 0; k < 4; ++k) v[k] = lh[4 * t + k];
    v[1] += v[0]; v[2] += v[1]; v[3] += v[2];
    ss[t] = v[3];
    __syncthreads();
    for (int d = 1; d < 256; d <<= 1) {
        const int add = (t >= d) ? ss[t - d] : 0;
        __syncthreads();
        ss[t] += add;
        __syncthreads();
    }
    const int excl = ss[t] - v[3];
    lex[4 * t]     = excl;
    lex[4 * t + 1] = excl + v[0];
    lex[4 * t + 2] = excl + v[1];
    lex[4 * t + 3] = excl + v[2];
    __syncthreads();

    const size_t cbase = (size_t)blockIdx.x * (NB + 1);
    for (int b = t; b <= NB; b += 256) start_table[cbase + b] = base + lex[b];
    __syncthreads();

    for (int i = base + t; i < end; i += 256) {
        const int2 e2 = ((const int2*)ei)[i];
        const int slot = atomicAdd(&lex[e2.y >> 7], 1);
        stage[base + slot] = ((uint32_t)e2.x << 8) | ((uint32_t)e2.y & 127u);
    }
}

// ---------------------------------------------------------------------------
// K2 (fused): blocks [0, NB): binB (CSR finalize, 128-node buckets);
// blocks [NB, ...): MFMA GEMM. boff = sum_c(start_table[c][b]-c*CHUNK).
// ---------------------------------------------------------------------------
__global__ __launch_bounds__(256) void gemm_binB(
    const float* __restrict__ x, const uint32_t* __restrict__ Wp,
    const float* __restrict__ aks, const float* __restrict__ akn,
    uint32_t* __restrict__ xpb, float* __restrict__ attn_self,
    float* __restrict__ attn_nei, const uint32_t* __restrict__ stage,
    const int* __restrict__ start_table, int* __restrict__ offsets,
    int* __restrict__ csr_src, int nc, int NB, int N, int E)
{
    __shared__ __align__(16) char smem[16896];   // max(gemm 16896, binB ~5.2K)
    const int t = threadIdx.x;

    if (blockIdx.x < NB) {                    // ---- binB part ----
        int* s0   = (int*)smem;               // [256]
        int* cum  = s0 + 256;                 // [257]
        int* ss   = cum + 257;                // [256]
        int* lcnt = ss + 256;                 // [128]
        int* lcur = lcnt + 128;               // [128]
        int* red  = lcur + 128;               // [256]
        const int b  = blockIdx.x;
        const int lo = b << 7;
        const int nn = min(N, lo + 128) - lo;

        int part = 0, len = 0;
        if (t < nc) {
            const size_t cb = (size_t)t * (NB + 1);
            const int a0 = start_table[cb + b];
            s0[t] = a0;
            len   = start_table[cb + b + 1] - a0;
            part  = a0 - t * CHUNK;
        }
        ss[t] = len;
        if (t < 128) lcnt[t] = 0;
        red[t] = part;
        if (t == 0 && b == 0) offsets[N] = E;
        __syncthreads();
        for (int d = 128; d > 0; d >>= 1) {
            if (t < d) red[t] += red[t + d];
            __syncthreads();
        }
        const int boff = red[0];
        for (int d = 1; d < 256; d <<= 1) {
            const int add = (t >= d) ? ss[t - d] : 0;
            __syncthreads();
            ss[t] += add;
            __syncthreads();
        }
        if (t == 0) cum[0] = 0;
        cum[t + 1] = ss[t];
        __syncthreads();
        const int T = cum[nc];

        for (int g = t; g < T; g += 256) {
            int loc = 0, hic = nc - 1;
            while (loc < hic) {
                const int mid = (loc + hic + 1) >> 1;
                if (cum[mid] <= g) loc = mid; else hic = mid - 1;
            }
            const uint32_t e = stage[s0[loc] + (g - cum[loc])];
            atomicAdd(&lcnt[e & 255u], 1);
        }
        __syncthreads();

        const int v = (t < 128) ? lcnt[t] : 0;
        ss[t] = v;
        __syncthreads();
        for (int d = 1; d < 256; d <<= 1) {
            const int add = (t >= d) ? ss[t - d] : 0;
            __syncthreads();
            ss[t] += add;
            __syncthreads();
        }
        const int nodeoff = boff + ss[t] - v;
        if (t < 128) lcur[t] = nodeoff;
        if (t < nn) offsets[lo + t] = nodeoff;
        __syncthreads();

        for (int g = t; g < T; g += 256) {
            int loc = 0, hic = nc - 1;
            while (loc < hic) {
                const int mid = (loc + hic + 1) >> 1;
                if (cum[mid] <= g) loc = mid; else hic = mid - 1;
            }
            const uint32_t e = stage[s0[loc] + (g - cum[loc])];
            const int slot = atomicAdd(&lcur[e & 255u], 1);
            csr_src[slot] = (int)(e >> 8);
        }
        return;
    }

    // ---- GEMM part ----
    ushort (*xs)[132] = (ushort(*)[132])smem;     // bf16 LDS: 16.9 KB
    const int blk = blockIdx.x - NB;
    const int w  = t >> 6;
    const int l  = t & 63;
    const int nb = blk * 64;

    const int row  = nb + w * 16 + (l & 15);
    const int rowc = min(row, N - 1);
    const int kg   = (l >> 4) * 8;
    const float* xrow = x + (size_t)rowc * 128 + kg;

    f32x4 acc[8] = {};
    #pragma unroll
    for (int kb = 0; kb < 4; ++kb) {
        const f32x4 x0 = __builtin_nontemporal_load((const f32x4*)(xrow + kb * 32));
        const f32x4 x1 = __builtin_nontemporal_load((const f32x4*)(xrow + kb * 32 + 4));
        union { short8 s; uint32_t u[4]; } A;
        A.u[0] = pack2(x0.x, x0.y); A.u[1] = pack2(x0.z, x0.w);
        A.u[2] = pack2(x1.x, x1.y); A.u[3] = pack2(x1.z, x1.w);
        #pragma unroll
        for (int cb = 0; cb < 8; ++cb) {
            union { short8 s; uint4 u; } B;
            B.u = *(const uint4*)&Wp[(((size_t)(kb * 8 + cb)) * 64 + l) * 4];
            acc[cb] = __builtin_amdgcn_mfma_f32_16x16x32_bf16(A.s, B.s, acc[cb], 0, 0, 0);
        }
    }

    const int r0 = (l >> 4) * 4;
    const int cl = l & 15;
    #pragma unroll
    for (int cb = 0; cb < 8; ++cb)
        #pragma unroll
        for (int r = 0; r < 4; ++r)
            xs[w * 16 + r0 + r][cb * 16 + cl] =
                (ushort)(pack2(acc[cb][r], 0.0f) & 0xffffu);
    __syncthreads();

    #pragma unroll
    for (int i = 0; i < 16; ++i) {
        const int idx = t + i * 256;           // 0..4095
        const int n = idx >> 6, q = idx & 63;
        const int gn = nb + n;
        if (gn < N)
            xpb[(size_t)gn * 64 + q] = *(const uint32_t*)&xs[n][2 * q];
    }

    {
        const int n = t & 63, h = t >> 6;
        const int gn = nb + n;
        if (gn < N) {
            float sv = 0.0f, sn = 0.0f;
            #pragma unroll
            for (int c = 0; c < 32; ++c) {
                const float v = __uint_as_float((uint32_t)xs[n][h * 32 + c] << 16);
                sv = fmaf(v, aks[c * 4 + h], sv);
                sn = fmaf(v, akn[c * 4 + h], sn);
            }
            attn_self[(size_t)gn * 4 + h] = sv;
            attn_nei [(size_t)gn * 4 + h] = sn;
        }
    }
}

// ---------------------------------------------------------------------------
// aggregate (established floor ~78 us): one wave/node, lane = 2 channels,
// VALU edge loop, unroll 8, NT out/alpha stores.
// ---------------------------------------------------------------------------
__global__ __launch_bounds__(256) void aggregate(
    const int* __restrict__ csr_src, const int* __restrict__ offsets,
    const uint32_t* __restrict__ xpb, const float* __restrict__ attn_self,
    const float* __restrict__ attn_nei, const float* __restrict__ bias,
    float* __restrict__ out, float* __restrict__ alpha_out,
    float* __restrict__ inv_arr, int N, int E)
{
    const int lane = threadIdx.x & 63;
    int node = blockIdx.x * 4 + (threadIdx.x >> 6);
    if (node >= N) return;
    node = __builtin_amdgcn_readfirstlane(node);

    const int hL = lane >> 4;        // head of this lane's 2 channels
    const int c0 = 2 * lane;

    const float asH = attn_self[(size_t)node * 4 + hL];
    const float anH = attn_nei [(size_t)node * 4 + hL];
    const float eS  = __expf(LEAKY(asH + anH));
    float sumE = eS;
    const uint32_t uS = xpb[(size_t)node * 64 + lane];
    float acc0 = eS * bf_lo(uS), acc1 = eS * bf_hi(uS);

    const int off0 = __builtin_amdgcn_readfirstlane(offsets[node]);
    const int deg  = __builtin_amdgcn_readfirstlane(offsets[node + 1]) - off0;
    const int* srcp = csr_src + off0;

    for (int j = 0; j < deg; j += 8) {
        int s[8];
        #pragma unroll
        for (int k = 0; k < 8; ++k) s[k] = srcp[min(j + k, deg - 1)];
        float a[8];
        #pragma unroll
        for (int k = 0; k < 8; ++k) a[k] = attn_nei[(size_t)s[k] * 4 + hL];
        uint32_t u[8];
        #pragma unroll
        for (int k = 0; k < 8; ++k) u[k] = xpb[(size_t)s[k] * 64 + lane];
        #pragma unroll
        for (int k = 0; k < 8; ++k) {
            const float v = (j + k < deg) ? __expf(LEAKY(asH + a[k])) : 0.0f;
            sumE += v;
            acc0 = fmaf(v, bf_lo(u[k]), acc0);
            acc1 = fmaf(v, bf_hi(u[k]), acc1);
        }
    }

    const float inv = 1.0f / sumE;
    union { float2 f; unsigned long long u; } o;
    o.f = make_float2(fmaf(acc0, inv, bias[c0]), fmaf(acc1, inv, bias[c0 + 1]));
    __builtin_nontemporal_store(o.u,
        (unsigned long long*)&out[(size_t)node * 128 + c0]);
    if ((lane & 15) == 0) {
        inv_arr[(size_t)node * 4 + hL] = inv;
        __builtin_nontemporal_store(eS * inv,
            &alpha_out[(size_t)(E + node) * 4 + hL]);
    }
}

// ---------------------------------------------------------------------------
// alpha for the E real edges: 2 edges/thread, nt int4 ei loads + nt stores.
// ---------------------------------------------------------------------------
__global__ __launch_bounds__(256) void alpha_kernel(
    const int* __restrict__ ei, const float* __restrict__ attn_self,
    const float* __restrict__ attn_nei, const float* __restrict__ inv_arr,
    float* __restrict__ alpha_out, int E)
{
    const int i0 = (blockIdx.x * 256 + threadIdx.x) * 2;
    if (i0 >= E) return;
    const int i1 = min(i0 + 1, E - 1);
    i32x4 e4;
    if (i0 + 1 < E) {
        e4 = __builtin_nontemporal_load((const i32x4*)(ei + 2 * (size_t)i0));
    } else {
        const i32x2 ea = __builtin_nontemporal_load((const i32x2*)(ei + 2 * (size_t)i0));
        e4.x = ea.x; e4.y = ea.y; e4.z = ea.x; e4.w = ea.y;
    }
    #pragma unroll
    for (int k = 0; k < 2; ++k) {
        const int i   = k ? i1 : i0;
        const int src = k ? e4.z : e4.x;
        const int tgt = k ? e4.w : e4.y;
        const float4 as4 = *(const float4*)&attn_self[(size_t)tgt * 4];
        const float4 an4 = *(const float4*)&attn_nei[(size_t)src * 4];
        const float4 iv4 = *(const float4*)&inv_arr[(size_t)tgt * 4];
        f32x4 a;
        a.x = __expf(LEAKY(as4.x + an4.x)) * iv4.x;
        a.y = __expf(LEAKY(as4.y + an4.y)) * iv4.y;
        a.z = __expf(LEAKY(as4.z + an4.z)) * iv4.z;
        a.w = __expf(LEAKY(as4.w + an4.w)) * iv4.w;
        __builtin_nontemporal_store(a, (f32x4*)&alpha_out[(size_t)i * 4]);
    }
}

// ---------------------------------------------------------------------------
extern "C" void kernel_launch(void* const* d_in, const int* in_sizes, int n_in,
                              void* d_out, int out_size, void* d_ws, size_t ws_size,
                              hipStream_t stream)
{
    const float* x    = (const float*)d_in[0];
    const int*   ei   = (const int*)d_in[1];
    const float* W    = (const float*)d_in[2];
    const float* aks  = (const float*)d_in[3];
    const float* akn  = (const float*)d_in[4];
    const float* bias = (const float*)d_in[5];

    const int N  = in_sizes[0] / 128;
    const int E  = in_sizes[1] / 2;
    const int NB = (N + 127) >> 7;            // buckets of 128 nodes
    const int nc = (E + CHUNK - 1) / CHUNK;

    float* out       = (float*)d_out;
    float* alpha_out = out + (size_t)N * 128;
    uint32_t* stage  = (uint32_t*)alpha_out;  // overlays alpha region (r7 note)

    char* p = (char*)d_ws;
    auto alloc = [&](size_t bytes) {
        char* r = p;
        p += (bytes + 255) & ~(size_t)255;
        return r;
    };
    uint32_t* xpb       = (uint32_t*)alloc((size_t)N * 64 * 4);
    uint32_t* Wp        = (uint32_t*)alloc((size_t)2048 * 16);
    float* attn_self    = (float*)alloc((size_t)N * 4 * 4);
    float* attn_nei     = (float*)alloc((size_t)N * 4 * 4);
    float* inv_arr      = (float*)alloc((size_t)N * 4 * 4);
    int*   offsets      = (int*)alloc((size_t)(N + 1) * 4);
    int*   csr_src      = (int*)alloc((size_t)E * 4);
    int*   start_table  = (int*)alloc((size_t)nc * (NB + 1) * 4);

    binA_wprep<<<nc + 8, 256, 0, stream>>>(ei, stage, start_table, W, Wp,
                                           nc, NB, E);
    gemm_binB<<<NB + (N + 63) / 64, 256, 0, stream>>>(
        x, Wp, aks, akn, xpb, attn_self, attn_nei,
        stage, start_table, offsets, csr_src, nc, NB, N, E);
    aggregate<<<(N + 3) / 4, 256, 0, stream>>>(csr_src, offsets, xpb,
                                               attn_self, attn_nei, bias, out,
                                               alpha_out, inv_arr, N, E);
    alpha_kernel<<<((E + 1) / 2 + 255) / 256, 256, 0, stream>>>(
        ei, attn_self, attn_nei, inv_arr, alpha_out, E);
}